// Round 11
// baseline (694.234 us; speedup 1.0000x reference)
//
#include <hip/hip_runtime.h>
#include <hip/hip_cooperative_groups.h>
#include <stdint.h>

namespace cg = cooperative_groups;

// PinConv pipeline, Round 11: single cooperative MEGA-KERNEL. All 9 stages
// become grid.sync()-separated phases (block-stride loops) — removes ~8
// dispatch boundaries (~10us each measured as the gap between sum-of-kernels
// ~140us and dur_us ~245us). Fallback to the multi-kernel path if the
// cooperative launch is rejected.

#define BN_EPS 1e-5f
#define NSLOT 32

typedef __attribute__((ext_vector_type(8))) short bf16x8;
typedef __attribute__((ext_vector_type(4))) float f32x4;

static __device__ __forceinline__ unsigned short f2bf(float f) {
    uint32_t u = __builtin_bit_cast(uint32_t, f);
    u += 0x7fffu + ((u >> 16) & 1u);          // round-to-nearest-even
    return (unsigned short)(u >> 16);
}
static __device__ __forceinline__ float bf_lo(uint32_t u) {
    return __builtin_bit_cast(float, u << 16);
}
static __device__ __forceinline__ float bf_hi(uint32_t u) {
    return __builtin_bit_cast(float, u & 0xffff0000u);
}

// one LDS union for all phases (28672 B -> 4-5 blocks/CU)
union Smem {
    struct { unsigned short As[64 * 72]; unsigned short Bs[128 * 72];
             float bs[128]; float bq[128]; } g;              // gemm
    struct { int hcnt[128]; int hbase[128]; } b;             // hist / bin
    struct { int hist[512]; int wpre[4]; } r;                // refine / coffs
    struct { float sa[128]; float sb[128]; } f;              // finalize
};

struct P {
    const float *feat, *w, *Qw, *Qb, *Ww, *Wb, *gamma2, *beta2;
    const int *src, *dst;
    float* out;
    float* y1; unsigned short *featb, *aggb, *h_bf;
    int4* tmp; int2* epack; int *offs, *coffs, *gcur;
    float* coefs; double* stats; int* ccnt;
    int N, E, CB, HB, GB, NB, AB, ZI;
    double invN;
};

// ---------------------------------------------------------------------------
static __device__ __forceinline__ void cast_body(
    int u, const float* __restrict__ feat, unsigned short* __restrict__ featb, int nf)
{
    int i = (u * 256 + threadIdx.x) * 4;
    if (i + 3 < nf) {
        float4 v = *(const float4*)(feat + i);
        ushort4 o;
        o.x = f2bf(v.x); o.y = f2bf(v.y); o.z = f2bf(v.z); o.w = f2bf(v.w);
        *(ushort4*)(featb + i) = o;
    } else {
        for (int j = i; j < nf; ++j) featb[j] = f2bf(feat[j]);
    }
}

static __device__ __forceinline__ void hist_body(
    Smem& sm, int u, const int* __restrict__ dst, int* __restrict__ ccnt, int E)
{
    const int tid = threadIdx.x;
    __syncthreads();                                   // guard smem reuse
    if (tid < 128) sm.b.hcnt[tid] = 0;
    __syncthreads();
    const int base_e = u * 2048;
#pragma unroll
    for (int j = 0; j < 8; ++j) {
        int e = base_e + j * 256 + tid;
        if (e < E) atomicAdd(&sm.b.hcnt[dst[e] >> 9], 1);
    }
    __syncthreads();
    if (tid < 128 && sm.b.hcnt[tid] > 0) atomicAdd(&ccnt[tid], sm.b.hcnt[tid]);
}

static __device__ __forceinline__ void coffs_body(
    Smem& sm, const int* __restrict__ ccnt, int* __restrict__ coffs,
    int* __restrict__ gcur, int* __restrict__ offs, int N, int E)
{
    const int t = threadIdx.x;
    __syncthreads();
    int v = 0, incl = 0;
    if (t < 128) {
        v = ccnt[t];
        incl = v;
#pragma unroll
        for (int o = 1; o < 64; o <<= 1) {
            int u = __shfl_up(incl, o, 64);
            if ((t & 63) >= o) incl += u;
        }
        if (t == 63) sm.r.wpre[0] = incl;
    }
    __syncthreads();
    if (t < 128) {
        int excl = incl - v + ((t >= 64) ? sm.r.wpre[0] : 0);
        coffs[t] = excl;
        gcur[t]  = excl;
        if (t == 127) { coffs[128] = excl + v; offs[N] = E; }
    }
}

static __device__ __forceinline__ void bin_body(
    Smem& sm, int bid,
    const int* __restrict__ src, const int* __restrict__ dst,
    const float* __restrict__ w, int* __restrict__ gcur,
    int4* __restrict__ tmp, int E)
{
    const int tid = threadIdx.x;
    __syncthreads();                                   // guard smem reuse
    if (tid < 128) sm.b.hcnt[tid] = 0;
    __syncthreads();

    int d8[8], s8[8], slot8[8];
    float w8[8];
#pragma unroll
    for (int j = 0; j < 8; ++j) {
        int e = bid * 2048 + j * 256 + tid;
        if (e < E) {
            d8[j] = dst[e]; s8[j] = src[e]; w8[j] = w[e];
            slot8[j] = atomicAdd(&sm.b.hcnt[d8[j] >> 9], 1);
        } else d8[j] = -1;
    }
    __syncthreads();
    if (tid < 128 && sm.b.hcnt[tid] > 0)
        sm.b.hbase[tid] = atomicAdd(&gcur[tid], sm.b.hcnt[tid]);
    __syncthreads();
#pragma unroll
    for (int j = 0; j < 8; ++j) {
        if (d8[j] >= 0) {
            int pos = sm.b.hbase[d8[j] >> 9] + slot8[j];
            tmp[pos] = make_int4(s8[j], __float_as_int(w8[j]), d8[j], 0);
        }
    }
}

template<int K>
static __device__ __forceinline__ void gemm_body(
    Smem& sm, int bid,
    const unsigned short* __restrict__ A_lo,
    const unsigned short* __restrict__ A_hi,
    const float* __restrict__ B,
    const float* __restrict__ bias,
    float* __restrict__ Y,
    double* __restrict__ sum, double* __restrict__ sumsq, int N)
{
    constexpr int SA = 72;
    const int tid  = threadIdx.x;
    const int lane = tid & 63;
    const int wv   = tid >> 6;
    const int wr   = wv >> 1;
    const int wc   = wv & 1;
    const int m15  = lane & 15;
    const int quad = lane >> 4;
    const int r0   = bid * 64;

    __syncthreads();                                   // guard smem reuse
    if (tid < 128) { sm.g.bs[tid] = 0.f; sm.g.bq[tid] = 0.f; }

    f32x4 acc[2][4];
#pragma unroll
    for (int rt = 0; rt < 2; ++rt)
#pragma unroll
        for (int ct = 0; ct < 4; ++ct)
            acc[rt][ct] = (f32x4){0.f, 0.f, 0.f, 0.f};

    for (int kc = 0; kc < K; kc += 64) {
        const unsigned short* Ap = (kc < 128) ? A_lo : A_hi;
        const int koff = kc & 127;
#pragma unroll
        for (int i = 0; i < 2; ++i) {
            int idx = i * 256 + tid;
            int row = idx >> 3, seg = idx & 7;
            int gr  = r0 + row; if (gr >= N) gr = N - 1;
            uint4 v = *(const uint4*)(Ap + (size_t)gr * 128 + koff + seg * 8);
            *(uint4*)(sm.g.As + row * SA + seg * 8) = v;
        }
#pragma unroll
        for (int i = 0; i < 8; ++i) {
            int idx = i * 256 + tid;
            int row = idx >> 4, seg = idx & 15;
            float4 v = *(const float4*)(B + (size_t)row * K + kc + seg * 4);
            ushort4 o;
            o.x = f2bf(v.x); o.y = f2bf(v.y); o.z = f2bf(v.z); o.w = f2bf(v.w);
            *(ushort4*)(sm.g.Bs + row * SA + seg * 4) = o;
        }
        __syncthreads();

#pragma unroll
        for (int ks = 0; ks < 64; ks += 32) {
            bf16x8 af[2], bfr[4];
#pragma unroll
            for (int rt = 0; rt < 2; ++rt)
                af[rt] = *(const bf16x8*)(sm.g.As + (wr * 32 + rt * 16 + m15) * SA + ks + quad * 8);
#pragma unroll
            for (int ct = 0; ct < 4; ++ct)
                bfr[ct] = *(const bf16x8*)(sm.g.Bs + (wc * 64 + ct * 16 + m15) * SA + ks + quad * 8);
#pragma unroll
            for (int rt = 0; rt < 2; ++rt)
#pragma unroll
                for (int ct = 0; ct < 4; ++ct)
                    acc[rt][ct] = __builtin_amdgcn_mfma_f32_16x16x32_bf16(
                        af[rt], bfr[ct], acc[rt][ct], 0, 0, 0);
        }
        __syncthreads();
    }

#pragma unroll
    for (int ct = 0; ct < 4; ++ct) {
        int col = wc * 64 + ct * 16 + m15;
        float bz = bias[col];
        float s = 0.f, q = 0.f;
#pragma unroll
        for (int rt = 0; rt < 2; ++rt) {
#pragma unroll
            for (int reg = 0; reg < 4; ++reg) {
                int row = r0 + wr * 32 + rt * 16 + quad * 4 + reg;
                float v = fmaxf(acc[rt][ct][reg] + bz, 0.f);
                if (row < N) {
                    Y[(size_t)row * 128 + col] = v;
                } else {
                    v = 0.f;
                }
                s += v; q = fmaf(v, v, q);
            }
        }
        s += __shfl_xor(s, 16, 64); s += __shfl_xor(s, 32, 64);
        q += __shfl_xor(q, 16, 64); q += __shfl_xor(q, 32, 64);
        if (quad == 0) {
            atomicAdd(&sm.g.bs[col], s);
            atomicAdd(&sm.g.bq[col], q);
        }
    }
    __syncthreads();
    if (tid < 128) {
        const int slot = (bid & (NSLOT - 1)) * 128;
        atomicAdd(&sum[slot + tid],   (double)sm.g.bs[tid]);
        atomicAdd(&sumsq[slot + tid], (double)sm.g.bq[tid]);
    }
}

static __device__ __forceinline__ void bn_coef_body(
    const double* __restrict__ sum, const double* __restrict__ sumsq,
    const float* __restrict__ gamma, const float* __restrict__ beta,
    float* __restrict__ a, float* __restrict__ b, double invN)
{
    const int t = threadIdx.x;
    if (t >= 128) return;
    double ms = 0.0, qs = 0.0;
#pragma unroll
    for (int s = 0; s < NSLOT; ++s) {
        ms += sum[s * 128 + t];
        qs += sumsq[s * 128 + t];
    }
    float mean = (float)(ms * invN);
    float var  = (float)(qs * invN) - mean * mean;
    float sc = rsqrtf(var + BN_EPS) * gamma[t];
    a[t] = sc;
    b[t] = fmaf(-mean, sc, beta[t]);
}

static __device__ __forceinline__ void apply_body(
    int u, const float* __restrict__ y,
    const float* __restrict__ a, const float* __restrict__ b,
    unsigned short* __restrict__ h, int n)
{
    int i = (u * 256 + threadIdx.x) * 4;
    if (i >= n) return;
    int c = i & 127;
    float4 v  = *(const float4*)(y + i);
    float4 av = *(const float4*)(a + c);
    float4 bv = *(const float4*)(b + c);
    ushort4 o;
    o.x = f2bf(fmaf(av.x, v.x, bv.x));
    o.y = f2bf(fmaf(av.y, v.y, bv.y));
    o.z = f2bf(fmaf(av.z, v.z, bv.z));
    o.w = f2bf(fmaf(av.w, v.w, bv.w));
    *(ushort4*)(h + i) = o;
}

static __device__ __forceinline__ void refine_body(
    Smem& sm, int b,
    const int4* __restrict__ tmp, const int* __restrict__ coffs,
    int* __restrict__ offs, int2* __restrict__ epack, int N)
{
    const int d0   = b << 9;
    const int dlim = min(512, N - d0);
    const int tid  = threadIdx.x;
    const int lane = tid & 63, wv = tid >> 6;
    const int start = coffs[b];
    const int end   = coffs[b + 1];

    __syncthreads();                                   // guard smem reuse
    sm.r.hist[tid] = 0; sm.r.hist[tid + 256] = 0;
    __syncthreads();

    for (int p = start + tid; p < end; p += 256)
        atomicAdd(&sm.r.hist[tmp[p].z - d0], 1);
    __syncthreads();

    int v0 = sm.r.hist[2 * tid], v1 = sm.r.hist[2 * tid + 1];
    int s = v0 + v1;
    int incl = s;
#pragma unroll
    for (int o = 1; o < 64; o <<= 1) {
        int t = __shfl_up(incl, o, 64);
        if (lane >= o) incl += t;
    }
    if (lane == 63) sm.r.wpre[wv] = incl;
    __syncthreads();
    if (tid == 0) {
        int r = 0;
#pragma unroll
        for (int i = 0; i < 4; ++i) { int t = sm.r.wpre[i]; sm.r.wpre[i] = r; r += t; }
    }
    __syncthreads();
    int e0 = start + sm.r.wpre[wv] + incl - s;
    if (2 * tid < dlim)     offs[d0 + 2 * tid]     = e0;
    if (2 * tid + 1 < dlim) offs[d0 + 2 * tid + 1] = e0 + v0;
    __syncthreads();
    sm.r.hist[2 * tid]     = e0;
    sm.r.hist[2 * tid + 1] = e0 + v0;
    __syncthreads();

    for (int p = start + tid; p < end; p += 256) {
        int4 rec = tmp[p];
        int pos = atomicAdd(&sm.r.hist[rec.z - d0], 1);
        epack[pos] = make_int2(rec.x, rec.y);
    }
}

static __device__ __forceinline__ void gather_row(
    int r, int lane,
    const unsigned short* __restrict__ h,
    const int* __restrict__ offs, const int2* __restrict__ epack,
    unsigned short* __restrict__ aggb)
{
    int p = offs[r];
    const int end = offs[r + 1];
    float nx = 0.f, ny = 0.f, den = 0.f;
    for (; p + 3 < end; p += 4) {
        int2 e0 = epack[p],     e1 = epack[p + 1];
        int2 e2 = epack[p + 2], e3 = epack[p + 3];
        uint32_t u0 = *(const uint32_t*)(h + (size_t)e0.x * 128 + 2 * lane);
        uint32_t u1 = *(const uint32_t*)(h + (size_t)e1.x * 128 + 2 * lane);
        uint32_t u2 = *(const uint32_t*)(h + (size_t)e2.x * 128 + 2 * lane);
        uint32_t u3 = *(const uint32_t*)(h + (size_t)e3.x * 128 + 2 * lane);
        float w0 = __int_as_float(e0.y), w1 = __int_as_float(e1.y);
        float w2 = __int_as_float(e2.y), w3 = __int_as_float(e3.y);
        nx = fmaf(w0, bf_lo(u0), nx); ny = fmaf(w0, bf_hi(u0), ny);
        nx = fmaf(w1, bf_lo(u1), nx); ny = fmaf(w1, bf_hi(u1), ny);
        nx = fmaf(w2, bf_lo(u2), nx); ny = fmaf(w2, bf_hi(u2), ny);
        nx = fmaf(w3, bf_lo(u3), nx); ny = fmaf(w3, bf_hi(u3), ny);
        den += (w0 + w1) + (w2 + w3);
    }
    for (; p < end; ++p) {
        int2 e0 = epack[p];
        float w0 = __int_as_float(e0.y);
        uint32_t u0 = *(const uint32_t*)(h + (size_t)e0.x * 128 + 2 * lane);
        nx = fmaf(w0, bf_lo(u0), nx); ny = fmaf(w0, bf_hi(u0), ny);
        den += w0;
    }
    float2 outv;
    if (den != 0.f) {
        float inv = 1.f / den;
        outv.x = nx * inv; outv.y = ny * inv;
    } else {
        uint32_t u = *(const uint32_t*)(h + (size_t)r * 128 + 2 * lane);
        outv.x = bf_lo(u); outv.y = bf_hi(u);
    }
    ushort2 ao; ao.x = f2bf(outv.x); ao.y = f2bf(outv.y);
    *(ushort2*)&aggb[(size_t)r * 128 + 2 * lane] = ao;
}

static __device__ __forceinline__ void final_row(
    int r, int lane, const float* __restrict__ Y2,
    const float* sa, const float* sb, float* __restrict__ out)
{
    const size_t base = (size_t)r * 128;
    float v0 = fmaf(sa[lane],      Y2[base + lane],      sb[lane]);
    float v1 = fmaf(sa[lane + 64], Y2[base + lane + 64], sb[lane + 64]);
    float ss = fmaf(v0, v0, v1 * v1);
#pragma unroll
    for (int o = 32; o; o >>= 1) ss += __shfl_xor(ss, o, 64);
    float nrm = sqrtf(ss);
    float inv = (nrm == 0.f) ? 1.f : 1.f / nrm;
    out[base + lane]      = v0 * inv;
    out[base + lane + 64] = v1 * inv;
}

// ---------------------------------------------------------------------------
// THE MEGA-KERNEL
__global__ __launch_bounds__(256) void mega(P p)
{
    cg::grid_group grid = cg::this_grid();
    __shared__ Smem sm;
    const int tid  = threadIdx.x;
    const int nb   = gridDim.x;
    const int wv   = tid >> 6, lane = tid & 63;

    // phase Z: zero stats + ccnt
    {
        int* z = (int*)p.stats;
        for (int i = blockIdx.x * 256 + tid; i < p.ZI; i += nb * 256) z[i] = 0;
    }
    grid.sync();

    // phase 0: cast feat || coarse dst histogram
    for (int u = blockIdx.x; u < p.CB + p.HB; u += nb) {
        if (u < p.CB) cast_body(u, p.feat, p.featb, p.N * 128);
        else          hist_body(sm, u - p.CB, p.dst, p.ccnt, p.E);
    }
    grid.sync();

    // phase 1: bucket scan (block 0)
    if (blockIdx.x == 0) coffs_body(sm, p.ccnt, p.coffs, p.gcur, p.offs, p.N, p.E);
    grid.sync();

    // phase 2: bin || gemm1
    for (int u = blockIdx.x; u < p.HB + p.GB; u += nb) {
        if (u < p.HB) bin_body(sm, u, p.src, p.dst, p.w, p.gcur, p.tmp, p.E);
        else          gemm_body<128>(sm, u - p.HB, p.featb, p.featb, p.Qw, p.Qb,
                                     p.y1, p.stats, p.stats + NSLOT * 128, p.N);
    }
    grid.sync();

    // phase 3: bn coefs 1 (block 0)
    if (blockIdx.x == 0)
        bn_coef_body(p.stats, p.stats + NSLOT * 128, p.gamma2, p.beta2,
                     p.coefs, p.coefs + 128, p.invN);
    grid.sync();

    // phase 4: refine || apply bn
    for (int u = blockIdx.x; u < p.NB + p.AB; u += nb) {
        if (u < p.NB) refine_body(sm, u, p.tmp, p.coffs, p.offs, p.epack, p.N);
        else          apply_body(u - p.NB, p.y1, p.coefs, p.coefs + 128,
                                 p.h_bf, p.N * 128);
    }
    grid.sync();

    // phase 5: gather
    {
        const int UN = (p.N + 3) >> 2;
        for (int u = blockIdx.x; u < UN; u += nb) {
            int r = u * 4 + wv;
            if (r < p.N) gather_row(r, lane, p.h_bf, p.offs, p.epack, p.aggb);
        }
    }
    grid.sync();

    // phase 6: gemm2
    for (int u = blockIdx.x; u < p.GB; u += nb)
        gemm_body<256>(sm, u, p.featb, p.aggb, p.Ww, p.Wb, p.y1,
                       p.stats + 2 * NSLOT * 128, p.stats + 3 * NSLOT * 128, p.N);
    grid.sync();

    // phase 7: bn coefs 2 (block 0)
    if (blockIdx.x == 0)
        bn_coef_body(p.stats + 2 * NSLOT * 128, p.stats + 3 * NSLOT * 128,
                     p.gamma2, p.beta2, p.coefs + 256, p.coefs + 384, p.invN);
    grid.sync();

    // phase 8: finalize (bn2 affine + row L2 norm)
    {
        __syncthreads();
        if (tid < 128) { sm.f.sa[tid] = p.coefs[256 + tid];
                         sm.f.sb[tid] = p.coefs[384 + tid]; }
        __syncthreads();
        const int UN = (p.N + 3) >> 2;
        for (int u = blockIdx.x; u < UN; u += nb) {
            int r = u * 4 + wv;
            if (r < p.N) final_row(r, lane, p.y1, sm.f.sa, sm.f.sb, p.out);
        }
    }
}

// ---------------------------------------------------------------------------
// Fallback multi-kernel path (round-10 structure), reusing the same bodies.
__global__ __launch_bounds__(256) void fk_pre(P p)
{
    __shared__ Smem sm;
    if ((int)blockIdx.x < p.CB) cast_body(blockIdx.x, p.feat, p.featb, p.N * 128);
    else hist_body(sm, blockIdx.x - p.CB, p.dst, p.ccnt, p.E);
}
__global__ __launch_bounds__(256) void fk_coffs(P p)
{
    __shared__ Smem sm;
    coffs_body(sm, p.ccnt, p.coffs, p.gcur, p.offs, p.N, p.E);
}
__global__ __launch_bounds__(256) void fk_bin_gemm(P p)
{
    __shared__ Smem sm;
    if ((int)blockIdx.x < p.HB)
        bin_body(sm, blockIdx.x, p.src, p.dst, p.w, p.gcur, p.tmp, p.E);
    else
        gemm_body<128>(sm, blockIdx.x - p.HB, p.featb, p.featb, p.Qw, p.Qb,
                       p.y1, p.stats, p.stats + NSLOT * 128, p.N);
}
__global__ __launch_bounds__(128) void fk_bn1(P p)
{
    bn_coef_body(p.stats, p.stats + NSLOT * 128, p.gamma2, p.beta2,
                 p.coefs, p.coefs + 128, p.invN);
}
__global__ __launch_bounds__(256) void fk_refine_apply(P p)
{
    __shared__ Smem sm;
    if ((int)blockIdx.x < p.NB)
        refine_body(sm, blockIdx.x, p.tmp, p.coffs, p.offs, p.epack, p.N);
    else
        apply_body(blockIdx.x - p.NB, p.y1, p.coefs, p.coefs + 128,
                   p.h_bf, p.N * 128);
}
__global__ __launch_bounds__(256) void fk_gather(P p)
{
    const int r = (int)((blockIdx.x * 256u + threadIdx.x) >> 6);
    if (r < p.N) gather_row(r, threadIdx.x & 63, p.h_bf, p.offs, p.epack, p.aggb);
}
__global__ __launch_bounds__(256) void fk_gemm2(P p)
{
    __shared__ Smem sm;
    gemm_body<256>(sm, blockIdx.x, p.featb, p.aggb, p.Ww, p.Wb, p.y1,
                   p.stats + 2 * NSLOT * 128, p.stats + 3 * NSLOT * 128, p.N);
}
__global__ __launch_bounds__(128) void fk_bn2(P p)
{
    bn_coef_body(p.stats + 2 * NSLOT * 128, p.stats + 3 * NSLOT * 128,
                 p.gamma2, p.beta2, p.coefs + 256, p.coefs + 384, p.invN);
}
__global__ __launch_bounds__(256) void fk_finalize(P p)
{
    __shared__ float sa[128], sb[128];
    const int t = threadIdx.x;
    if (t < 128) { sa[t] = p.coefs[256 + t]; sb[t] = p.coefs[384 + t]; }
    __syncthreads();
    const int r = (int)((blockIdx.x * 256u + t) >> 6);
    if (r < p.N) final_row(r, t & 63, p.y1, sa, sb, p.out);
}

// ---------------------------------------------------------------------------
extern "C" void kernel_launch(void* const* d_in, const int* in_sizes, int n_in,
                              void* d_out, int out_size, void* d_ws, size_t ws_size,
                              hipStream_t stream)
{
    const int N = in_sizes[0] / 128;   // 50000
    const int E = in_sizes[1];         // 800000

    // workspace layout
    float*          y1    = (float*)d_ws;                            // N*128 f32
    unsigned short* featb = (unsigned short*)(y1 + (size_t)N * 128); // N*128 bf16
    unsigned short* aggb  = featb + (size_t)N * 128;                 // N*128 bf16
    unsigned short* h_bf  = aggb + (size_t)N * 128;                  // N*128 bf16
    int4*  tmp    = (int4*)(h_bf + (size_t)N * 128);                 // E
    int2*  epack  = (int2*)(tmp + E);                                // E
    int*   offs   = (int*)(epack + E);                               // N+1
    int*   coffs  = offs + (N + 1);                                  // 129
    int*   gcur   = coffs + 129;                                     // 128
    float* coefs  = (float*)(gcur + 128);                            // 512
    uintptr_t sp  = ((uintptr_t)(coefs + 512) + 7) & ~(uintptr_t)7;
    double* stats = (double*)sp;                                     // 4*NSLOT*128
    int*    ccnt  = (int*)(stats + 4 * NSLOT * 128);                 // 128

    P p;
    p.feat = (const float*)d_in[0]; p.w = (const float*)d_in[1];
    p.Qw = (const float*)d_in[2];   p.Qb = (const float*)d_in[3];
    p.Ww = (const float*)d_in[4];   p.Wb = (const float*)d_in[5];
    p.gamma2 = (const float*)d_in[6]; p.beta2 = (const float*)d_in[7];
    p.src = (const int*)d_in[8];    p.dst = (const int*)d_in[9];
    p.out = (float*)d_out;
    p.y1 = y1; p.featb = featb; p.aggb = aggb; p.h_bf = h_bf;
    p.tmp = tmp; p.epack = epack; p.offs = offs; p.coffs = coffs; p.gcur = gcur;
    p.coefs = coefs; p.stats = stats; p.ccnt = ccnt;
    p.N = N; p.E = E;
    p.CB = (N * 128 / 4 + 255) / 256;          // 6250 cast tiles
    p.HB = (E + 2047) / 2048;                  // 391 hist/bin tiles
    p.GB = (N + 63) / 64;                      // 782 gemm tiles
    p.NB = (N + 511) >> 9;                     // 98 buckets
    p.AB = (N * 128 / 4 + 255) / 256;          // 6250 apply tiles
    p.ZI = 4 * NSLOT * 128 * 2 + 128;          // ints to zero (stats + ccnt)
    p.invN = 1.0 / (double)N;

    // cooperative mega-launch; grid = occupancy-derived co-resident count
    int bpc = 0;
    hipError_t oe = hipOccupancyMaxActiveBlocksPerMultiprocessor(&bpc, mega, 256, 0);
    hipError_t le = hipErrorUnknown;
    if (oe == hipSuccess && bpc >= 1) {
        int G = bpc * 256;                     // 256 CUs on MI355X
        if (G > 2048) G = 2048;
        void* kargs[] = { (void*)&p };
        le = hipLaunchCooperativeKernel(mega, dim3(G), dim3(256), kargs, 0, stream);
    }
    if (le != hipSuccess) {
        // fallback: multi-kernel path (round-10 structure)
        hipMemsetAsync(stats, 0, (size_t)p.ZI * sizeof(int), stream);
        fk_pre<<<p.CB + p.HB, 256, 0, stream>>>(p);
        fk_coffs<<<1, 256, 0, stream>>>(p);
        fk_bin_gemm<<<p.HB + p.GB, 256, 0, stream>>>(p);
        fk_bn1<<<1, 128, 0, stream>>>(p);
        fk_refine_apply<<<p.NB + p.AB, 256, 0, stream>>>(p);
        fk_gather<<<(N * 64 + 255) / 256, 256, 0, stream>>>(p);
        fk_gemm2<<<p.GB, 256, 0, stream>>>(p);
        fk_bn2<<<1, 128, 0, stream>>>(p);
        fk_finalize<<<(N * 64 + 255) / 256, 256, 0, stream>>>(p);
    }
}

// Round 12
// 299.503 us; speedup vs baseline: 2.3180x; 2.3180x over previous
//
#include <hip/hip_runtime.h>
#include <stdint.h>

// PinConv pipeline, Round 12: back to multi-kernel (grid.sync() cost ~50us on
// 8 XCDs made the cooperative mega 3x SLOWER). Structural dispatch reduction
// instead (10 -> 6 nodes):
//  - affine-commute: agg = a*(sum w*y / sum w)+b, so gather consumes RAW relu
//    output (yb bf16, written by gemm1 epilogue) -> apply_bn stage eliminated.
//  - fixed-capacity buckets (CAP=10240, 22 sigma headroom): no global
//    histogram, no scan -> k_pre-hist/k_coffs eliminated.
//  - bn coef computed by LAST-finishing block of each gemm dispatch
//    (threadfence + done counter, stats read via atomicAdd(p,0.0)).
// Chain: memset | fatA(cast||bin) | fatB(gemm1||refine,+bn1) | gather |
//        gemm2(+bn2) | finalize.

#define BN_EPS 1e-5f
#define NSLOT 32
#define CAP 10240

typedef __attribute__((ext_vector_type(8))) short bf16x8;
typedef __attribute__((ext_vector_type(4))) float f32x4;

static __device__ __forceinline__ unsigned short f2bf(float f) {
    uint32_t u = __builtin_bit_cast(uint32_t, f);
    u += 0x7fffu + ((u >> 16) & 1u);          // round-to-nearest-even
    return (unsigned short)(u >> 16);
}
static __device__ __forceinline__ float bf_lo(uint32_t u) {
    return __builtin_bit_cast(float, u << 16);
}
static __device__ __forceinline__ float bf_hi(uint32_t u) {
    return __builtin_bit_cast(float, u & 0xffff0000u);
}

union Smem {
    struct { unsigned short As[64 * 72]; unsigned short Bs[128 * 72];
             float bs[128]; float bq[128]; } g;              // gemm
    struct { int hcnt[128]; int hbase[128]; } b;             // bin
    struct { int hist[512]; int wpre[4]; } r;                // refine
    struct { float sa[128]; float sb[128]; } f;              // finalize
};

struct P {
    const float *feat, *w, *Qw, *Qb, *Ww, *Wb, *gamma2, *beta2;
    const int *src, *dst;
    float* out;
    float* y2; unsigned short *yb, *featb, *aggb;
    int2* tmp; int2* epack; int *offs, *ends;
    float* coefs; double* stats; int* gcur; int* dc;
    int N, E, CB, HB, GB, NB;
    double invN;
};

// ---------------------------------------------------------------------------
static __device__ __forceinline__ void cast_body(
    int u, const float* __restrict__ feat, unsigned short* __restrict__ featb, int nf)
{
    int i = (u * 256 + threadIdx.x) * 4;
    if (i + 3 < nf) {
        float4 v = *(const float4*)(feat + i);
        ushort4 o;
        o.x = f2bf(v.x); o.y = f2bf(v.y); o.z = f2bf(v.z); o.w = f2bf(v.w);
        *(ushort4*)(featb + i) = o;
    } else {
        for (int j = i; j < nf; ++j) featb[j] = f2bf(feat[j]);
    }
}

// bin: LDS bucket hist -> gcur cursor bump -> packed records at b*CAP + pos.
static __device__ __forceinline__ void bin_body(
    Smem& sm, int bid,
    const int* __restrict__ src, const int* __restrict__ dst,
    const float* __restrict__ w, int* __restrict__ gcur,
    int2* __restrict__ tmp, int E)
{
    const int tid = threadIdx.x;
    if (tid < 128) sm.b.hcnt[tid] = 0;
    __syncthreads();

    int d8[8], s8[8], slot8[8];
    float w8[8];
#pragma unroll
    for (int j = 0; j < 8; ++j) {
        int e = bid * 2048 + j * 256 + tid;
        if (e < E) {
            d8[j] = dst[e]; s8[j] = src[e]; w8[j] = w[e];
            slot8[j] = atomicAdd(&sm.b.hcnt[d8[j] >> 9], 1);
        } else d8[j] = -1;
    }
    __syncthreads();
    if (tid < 128 && sm.b.hcnt[tid] > 0)
        sm.b.hbase[tid] = atomicAdd(&gcur[tid], sm.b.hcnt[tid]);
    __syncthreads();
#pragma unroll
    for (int j = 0; j < 8; ++j) {
        if (d8[j] >= 0) {
            int bk  = d8[j] >> 9;
            int pos = sm.b.hbase[bk] + slot8[j];
            if (pos < CAP)   // 22-sigma headroom; guard vs silent OOB
                tmp[(size_t)bk * CAP + pos] =
                    make_int2(s8[j] | ((d8[j] & 511) << 18), __float_as_int(w8[j]));
        }
    }
}

// ---------------------------------------------------------------------------
// GEMM: Y = relu(A@B^T + bias). BF16OUT: store bf16 to Yh, else f32 to Yf.
// Col sum/sumsq (on f32 values) -> striped fp64 slots.
template<int K, bool BF16OUT>
static __device__ __forceinline__ void gemm_body(
    Smem& sm, int bid,
    const unsigned short* __restrict__ A_lo,
    const unsigned short* __restrict__ A_hi,
    const float* __restrict__ B,
    const float* __restrict__ bias,
    float* __restrict__ Yf, unsigned short* __restrict__ Yh,
    double* __restrict__ sum, double* __restrict__ sumsq, int N)
{
    constexpr int SA = 72;
    const int tid  = threadIdx.x;
    const int lane = tid & 63;
    const int wv   = tid >> 6;
    const int wr   = wv >> 1;
    const int wc   = wv & 1;
    const int m15  = lane & 15;
    const int quad = lane >> 4;
    const int r0   = bid * 64;

    if (tid < 128) { sm.g.bs[tid] = 0.f; sm.g.bq[tid] = 0.f; }

    f32x4 acc[2][4];
#pragma unroll
    for (int rt = 0; rt < 2; ++rt)
#pragma unroll
        for (int ct = 0; ct < 4; ++ct)
            acc[rt][ct] = (f32x4){0.f, 0.f, 0.f, 0.f};

    for (int kc = 0; kc < K; kc += 64) {
        const unsigned short* Ap = (kc < 128) ? A_lo : A_hi;
        const int koff = kc & 127;
#pragma unroll
        for (int i = 0; i < 2; ++i) {
            int idx = i * 256 + tid;
            int row = idx >> 3, seg = idx & 7;
            int gr  = r0 + row; if (gr >= N) gr = N - 1;
            uint4 v = *(const uint4*)(Ap + (size_t)gr * 128 + koff + seg * 8);
            *(uint4*)(sm.g.As + row * SA + seg * 8) = v;
        }
#pragma unroll
        for (int i = 0; i < 8; ++i) {
            int idx = i * 256 + tid;
            int row = idx >> 4, seg = idx & 15;
            float4 v = *(const float4*)(B + (size_t)row * K + kc + seg * 4);
            ushort4 o;
            o.x = f2bf(v.x); o.y = f2bf(v.y); o.z = f2bf(v.z); o.w = f2bf(v.w);
            *(ushort4*)(sm.g.Bs + row * SA + seg * 4) = o;
        }
        __syncthreads();

#pragma unroll
        for (int ks = 0; ks < 64; ks += 32) {
            bf16x8 af[2], bfr[4];
#pragma unroll
            for (int rt = 0; rt < 2; ++rt)
                af[rt] = *(const bf16x8*)(sm.g.As + (wr * 32 + rt * 16 + m15) * SA + ks + quad * 8);
#pragma unroll
            for (int ct = 0; ct < 4; ++ct)
                bfr[ct] = *(const bf16x8*)(sm.g.Bs + (wc * 64 + ct * 16 + m15) * SA + ks + quad * 8);
#pragma unroll
            for (int rt = 0; rt < 2; ++rt)
#pragma unroll
                for (int ct = 0; ct < 4; ++ct)
                    acc[rt][ct] = __builtin_amdgcn_mfma_f32_16x16x32_bf16(
                        af[rt], bfr[ct], acc[rt][ct], 0, 0, 0);
        }
        __syncthreads();
    }

#pragma unroll
    for (int ct = 0; ct < 4; ++ct) {
        int col = wc * 64 + ct * 16 + m15;
        float bz = bias[col];
        float s = 0.f, q = 0.f;
#pragma unroll
        for (int rt = 0; rt < 2; ++rt) {
#pragma unroll
            for (int reg = 0; reg < 4; ++reg) {
                int row = r0 + wr * 32 + rt * 16 + quad * 4 + reg;
                float v = fmaxf(acc[rt][ct][reg] + bz, 0.f);
                if (row < N) {
                    if (BF16OUT) Yh[(size_t)row * 128 + col] = f2bf(v);
                    else         Yf[(size_t)row * 128 + col] = v;
                } else {
                    v = 0.f;
                }
                s += v; q = fmaf(v, v, q);
            }
        }
        s += __shfl_xor(s, 16, 64); s += __shfl_xor(s, 32, 64);
        q += __shfl_xor(q, 16, 64); q += __shfl_xor(q, 32, 64);
        if (quad == 0) {
            atomicAdd(&sm.g.bs[col], s);
            atomicAdd(&sm.g.bq[col], q);
        }
    }
    __syncthreads();
    if (tid < 128) {
        const int slot = (bid & (NSLOT - 1)) * 128;
        atomicAdd(&sum[slot + tid],   (double)sm.g.bs[tid]);
        atomicAdd(&sumsq[slot + tid], (double)sm.g.bq[tid]);
    }
}

// bn tail: last-finishing block reduces 32 slots (coherent atomic reads).
static __device__ __forceinline__ void bn_tail(
    double* __restrict__ sum, double* __restrict__ sumsq,
    const float* __restrict__ gamma, const float* __restrict__ beta,
    float* __restrict__ a, float* __restrict__ b, double invN)
{
    const int t = threadIdx.x;
    if (t >= 128) return;
    double ms = 0.0, qs = 0.0;
#pragma unroll
    for (int s = 0; s < NSLOT; ++s) {
        ms += atomicAdd(&sum[s * 128 + t], 0.0);      // coherent cross-XCD read
        qs += atomicAdd(&sumsq[s * 128 + t], 0.0);
    }
    float mean = (float)(ms * invN);
    float var  = (float)(qs * invN) - mean * mean;
    float sc = rsqrtf(var + BN_EPS) * gamma[t];
    a[t] = sc;
    b[t] = fmaf(-mean, sc, beta[t]);
}

// ---------------------------------------------------------------------------
// refine: per bucket — LDS per-dst hist of this bucket's records, scan, write
// offs/ends, scatter to epack (bucket-local base b*CAP).
static __device__ __forceinline__ void refine_body(
    Smem& sm, int b,
    const int2* __restrict__ tmp, const int* __restrict__ gcur,
    int* __restrict__ offs, int* __restrict__ ends,
    int2* __restrict__ epack, int N)
{
    const int d0    = b << 9;
    const int dlim  = min(512, N - d0);
    const int tid   = threadIdx.x;
    const int lane  = tid & 63, wv = tid >> 6;
    const size_t base = (size_t)b * CAP;
    const int count = min(gcur[b], CAP);

    sm.r.hist[tid] = 0; sm.r.hist[tid + 256] = 0;
    __syncthreads();

    for (int i = tid; i < count; i += 256)
        atomicAdd(&sm.r.hist[(tmp[base + i].x >> 18) & 511], 1);
    __syncthreads();

    int v0 = sm.r.hist[2 * tid], v1 = sm.r.hist[2 * tid + 1];
    int s = v0 + v1;
    int incl = s;
#pragma unroll
    for (int o = 1; o < 64; o <<= 1) {
        int t = __shfl_up(incl, o, 64);
        if (lane >= o) incl += t;
    }
    if (lane == 63) sm.r.wpre[wv] = incl;
    __syncthreads();
    if (tid == 0) {
        int r = 0;
#pragma unroll
        for (int i = 0; i < 4; ++i) { int t = sm.r.wpre[i]; sm.r.wpre[i] = r; r += t; }
    }
    __syncthreads();
    int e0 = (int)base + sm.r.wpre[wv] + incl - s;
    if (2 * tid < dlim)     { offs[d0 + 2 * tid]     = e0;      ends[d0 + 2 * tid]     = e0 + v0; }
    if (2 * tid + 1 < dlim) { offs[d0 + 2 * tid + 1] = e0 + v0; ends[d0 + 2 * tid + 1] = e0 + v0 + v1; }
    __syncthreads();
    sm.r.hist[2 * tid]     = e0;
    sm.r.hist[2 * tid + 1] = e0 + v0;
    __syncthreads();

    for (int i = tid; i < count; i += 256) {
        int2 rec = tmp[base + i];
        int ld  = (rec.x >> 18) & 511;
        int pos = atomicAdd(&sm.r.hist[ld], 1);
        epack[pos] = make_int2(rec.x & 0x3FFFF, rec.y);
    }
}

// ---------------------------------------------------------------------------
// gather: one wave per dst row over RAW bf16 y; epilogue applies a1,b1.
static __device__ __forceinline__ void gather_row(
    int r, int lane,
    const unsigned short* __restrict__ yb,
    const int* __restrict__ offs, const int* __restrict__ ends,
    const int2* __restrict__ epack,
    const float* __restrict__ a1v, const float* __restrict__ b1v,
    unsigned short* __restrict__ aggb)
{
    int p = offs[r];
    const int end = ends[r];
    float nx = 0.f, ny = 0.f, den = 0.f;
    for (; p + 3 < end; p += 4) {
        int2 e0 = epack[p],     e1 = epack[p + 1];
        int2 e2 = epack[p + 2], e3 = epack[p + 3];
        uint32_t u0 = *(const uint32_t*)(yb + (size_t)e0.x * 128 + 2 * lane);
        uint32_t u1 = *(const uint32_t*)(yb + (size_t)e1.x * 128 + 2 * lane);
        uint32_t u2 = *(const uint32_t*)(yb + (size_t)e2.x * 128 + 2 * lane);
        uint32_t u3 = *(const uint32_t*)(yb + (size_t)e3.x * 128 + 2 * lane);
        float w0 = __int_as_float(e0.y), w1 = __int_as_float(e1.y);
        float w2 = __int_as_float(e2.y), w3 = __int_as_float(e3.y);
        nx = fmaf(w0, bf_lo(u0), nx); ny = fmaf(w0, bf_hi(u0), ny);
        nx = fmaf(w1, bf_lo(u1), nx); ny = fmaf(w1, bf_hi(u1), ny);
        nx = fmaf(w2, bf_lo(u2), nx); ny = fmaf(w2, bf_hi(u2), ny);
        nx = fmaf(w3, bf_lo(u3), nx); ny = fmaf(w3, bf_hi(u3), ny);
        den += (w0 + w1) + (w2 + w3);
    }
    for (; p < end; ++p) {
        int2 e0 = epack[p];
        float w0 = __int_as_float(e0.y);
        uint32_t u0 = *(const uint32_t*)(yb + (size_t)e0.x * 128 + 2 * lane);
        nx = fmaf(w0, bf_lo(u0), nx); ny = fmaf(w0, bf_hi(u0), ny);
        den += w0;
    }
    const float2 a = *(const float2*)&a1v[2 * lane];
    const float2 b = *(const float2*)&b1v[2 * lane];
    float yx, yy;
    if (den != 0.f) {
        float inv = 1.f / den;
        yx = nx * inv; yy = ny * inv;
    } else {
        uint32_t u = *(const uint32_t*)(yb + (size_t)r * 128 + 2 * lane);
        yx = bf_lo(u); yy = bf_hi(u);
    }
    ushort2 ao;
    ao.x = f2bf(fmaf(a.x, yx, b.x));
    ao.y = f2bf(fmaf(a.y, yy, b.y));
    *(ushort2*)&aggb[(size_t)r * 128 + 2 * lane] = ao;
}

static __device__ __forceinline__ void final_row(
    int r, int lane, const float* __restrict__ Y2,
    const float* sa, const float* sb, float* __restrict__ out)
{
    const size_t base = (size_t)r * 128;
    float v0 = fmaf(sa[lane],      Y2[base + lane],      sb[lane]);
    float v1 = fmaf(sa[lane + 64], Y2[base + lane + 64], sb[lane + 64]);
    float ss = fmaf(v0, v0, v1 * v1);
#pragma unroll
    for (int o = 32; o; o >>= 1) ss += __shfl_xor(ss, o, 64);
    float nrm = sqrtf(ss);
    float inv = (nrm == 0.f) ? 1.f : 1.f / nrm;
    out[base + lane]      = v0 * inv;
    out[base + lane + 64] = v1 * inv;
}

// ---------------------------------------------------------------------------
__global__ __launch_bounds__(256) void fatA(P p)   // cast || bin
{
    __shared__ Smem sm;
    if ((int)blockIdx.x < p.CB)
        cast_body(blockIdx.x, p.feat, p.featb, p.N * 128);
    else
        bin_body(sm, blockIdx.x - p.CB, p.src, p.dst, p.w, p.gcur, p.tmp, p.E);
}

__global__ __launch_bounds__(256) void fatB(P p)   // gemm1 || refine, +bn1 tail
{
    __shared__ Smem sm;
    __shared__ int lastflag;
    if ((int)blockIdx.x < p.GB)
        gemm_body<128, true>(sm, blockIdx.x, p.featb, p.featb, p.Qw, p.Qb,
                             nullptr, p.yb, p.stats, p.stats + NSLOT * 128, p.N);
    else
        refine_body(sm, blockIdx.x - p.GB, p.tmp, p.gcur, p.offs, p.ends,
                    p.epack, p.N);
    __syncthreads();
    if (threadIdx.x == 0) {
        __threadfence();
        int old = atomicAdd(&p.dc[0], 1);
        lastflag = (old == p.GB + p.NB - 1);
    }
    __syncthreads();
    if (lastflag)
        bn_tail(p.stats, p.stats + NSLOT * 128, p.gamma2, p.beta2,
                p.coefs, p.coefs + 128, p.invN);
}

__global__ __launch_bounds__(256) void k_gather(P p)
{
    const int r = (int)((blockIdx.x * 256u + threadIdx.x) >> 6);
    if (r < p.N)
        gather_row(r, threadIdx.x & 63, p.yb, p.offs, p.ends, p.epack,
                   p.coefs, p.coefs + 128, p.aggb);
}

__global__ __launch_bounds__(256) void k_gemm2(P p)  // +bn2 tail
{
    __shared__ Smem sm;
    __shared__ int lastflag;
    gemm_body<256, false>(sm, blockIdx.x, p.featb, p.aggb, p.Ww, p.Wb,
                          p.y2, nullptr,
                          p.stats + 2 * NSLOT * 128, p.stats + 3 * NSLOT * 128, p.N);
    __syncthreads();
    if (threadIdx.x == 0) {
        __threadfence();
        int old = atomicAdd(&p.dc[1], 1);
        lastflag = (old == p.GB - 1);
    }
    __syncthreads();
    if (lastflag)
        bn_tail(p.stats + 2 * NSLOT * 128, p.stats + 3 * NSLOT * 128,
                p.gamma2, p.beta2, p.coefs + 256, p.coefs + 384, p.invN);
}

__global__ __launch_bounds__(256) void k_finalize(P p)
{
    __shared__ float sa[128], sb[128];
    const int t = threadIdx.x;
    if (t < 128) { sa[t] = p.coefs[256 + t]; sb[t] = p.coefs[384 + t]; }
    __syncthreads();
    const int r = (int)((blockIdx.x * 256u + t) >> 6);
    if (r < p.N) final_row(r, t & 63, p.y2, sa, sb, p.out);
}

// ---------------------------------------------------------------------------
extern "C" void kernel_launch(void* const* d_in, const int* in_sizes, int n_in,
                              void* d_out, int out_size, void* d_ws, size_t ws_size,
                              hipStream_t stream)
{
    const int N = in_sizes[0] / 128;   // 50000
    const int E = in_sizes[1];         // 800000
    const int NB = (N + 511) >> 9;     // 98 buckets

    // workspace layout
    float*          y2    = (float*)d_ws;                            // N*128 f32
    unsigned short* yb    = (unsigned short*)(y2 + (size_t)N * 128); // N*128 bf16 (raw relu y1)
    unsigned short* featb = yb + (size_t)N * 128;                    // N*128 bf16
    unsigned short* aggb  = featb + (size_t)N * 128;                 // N*128 bf16
    int2*  tmp    = (int2*)(aggb + (size_t)N * 128);                 // NB*CAP
    int2*  epack  = tmp + (size_t)NB * CAP;                          // NB*CAP
    int*   offs   = (int*)(epack + (size_t)NB * CAP);                // N
    int*   ends   = offs + N;                                        // N
    float* coefs  = (float*)(ends + N);                              // 512
    uintptr_t sp  = ((uintptr_t)(coefs + 512) + 7) & ~(uintptr_t)7;
    double* stats = (double*)sp;                                     // 4*NSLOT*128 <- zeroed
    int*    gcur  = (int*)(stats + 4 * NSLOT * 128);                 // 128 <- zeroed
    int*    dc    = gcur + 128;                                      // 2   <- zeroed

    P p;
    p.feat = (const float*)d_in[0]; p.w = (const float*)d_in[1];
    p.Qw = (const float*)d_in[2];   p.Qb = (const float*)d_in[3];
    p.Ww = (const float*)d_in[4];   p.Wb = (const float*)d_in[5];
    p.gamma2 = (const float*)d_in[6]; p.beta2 = (const float*)d_in[7];
    p.src = (const int*)d_in[8];    p.dst = (const int*)d_in[9];
    p.out = (float*)d_out;
    p.y2 = y2; p.yb = yb; p.featb = featb; p.aggb = aggb;
    p.tmp = tmp; p.epack = epack; p.offs = offs; p.ends = ends;
    p.coefs = coefs; p.stats = stats; p.gcur = gcur; p.dc = dc;
    p.N = N; p.E = E;
    p.CB = (N * 128 / 4 + 255) / 256;          // 6250 cast tiles
    p.HB = (E + 2047) / 2048;                  // 391 bin tiles
    p.GB = (N + 63) / 64;                      // 782 gemm tiles
    p.NB = NB;
    p.invN = 1.0 / (double)N;

    // zero stats + gcur + dc (contiguous, ~132 KB)
    hipMemsetAsync(stats, 0,
                   4 * NSLOT * 128 * sizeof(double) + 130 * sizeof(int), stream);

    fatA<<<p.CB + p.HB, 256, 0, stream>>>(p);
    fatB<<<p.GB + p.NB, 256, 0, stream>>>(p);
    k_gather<<<(N * 64 + 255) / 256, 256, 0, stream>>>(p);
    k_gemm2<<<p.GB, 256, 0, stream>>>(p);
    k_finalize<<<(N * 64 + 255) / 256, 256, 0, stream>>>(p);
}